// Round 4
// baseline (18928.703 us; speedup 1.0000x reference)
//
#include <hip/hip_runtime.h>

// RNN: h_t = tanh(W_hh h_{t-1} + b_hh + W_xh emb[X_t] + b_xh)
// N=64, L=2048, V=32000, H=512.
//
// K1: Xh' = emb[X] @ W_xh^T + (b_xh + b_hh) -> written INTO d_out (fp16 MFMA, fp32 accum).
// K2: 16 WGs = 4 batch-groups x 4 col-slices. Per WG: 16 batch rows, 128 cols,
//     W slice = 128 VGPRs/wave (NO spill possible, no LDS W). Per step, h is
//     exchanged via global mailboxes (relaxed agent-scope atomics, monotonic
//     step flags, 2-buffer skew-1-safe protocol proven in R1). Own slice via
//     8 KB swizzled LDS. vmcnt drain covers only the 1 KB mailbox publish;
//     HBM out-stores are issued after the flag and never waited on.

typedef _Float16 half8 __attribute__((ext_vector_type(8)));
typedef float    f32x4 __attribute__((ext_vector_type(4)));

#define MFMA_F16(A,B,C) __builtin_amdgcn_mfma_f32_16x16x32_f16(A,B,C,0,0,0)

static __device__ __forceinline__ half8 cvt8(const float* p){
  const f32x4* q = (const f32x4*)p;
  f32x4 a = q[0], b = q[1];
  half8 r;
  r[0]=(_Float16)a[0]; r[1]=(_Float16)a[1]; r[2]=(_Float16)a[2]; r[3]=(_Float16)a[3];
  r[4]=(_Float16)b[0]; r[5]=(_Float16)b[1]; r[6]=(_Float16)b[2]; r[7]=(_Float16)b[3];
  return r;
}

static __device__ __forceinline__ float tanh_fast(float z){
  float e = __expf(2.0f*z);
  return 1.0f - 2.0f/(e + 1.0f);
}

// ---------------- Kernel 1: Xh' = E @ Wxh^T + (bxh + bhh) -> d_out ----------------
__global__ __launch_bounds__(256) void k_xh(
    const int* __restrict__ X, const float* __restrict__ emb,
    const float* __restrict__ Wxh, const float* __restrict__ bxh,
    const float* __restrict__ bhh, float* __restrict__ out)
{
  const int bid = blockIdx.x;
  const int bm = bid >> 3;
  const int bn = bid & 7;
  const int tid = threadIdx.x;
  const int w  = tid >> 6;
  const int l  = tid & 63;
  const int lr = l & 15, lq = l >> 4;

  const int mbase = bm*64 + (w>>1)*32;
  const int nbase = bn*64 + (w&1)*32;

  const int tok0 = X[mbase + lr];
  const int tok1 = X[mbase + 16 + lr];
  const int c0 = nbase + lr;
  const int c1 = nbase + 16 + lr;
  const float bs0 = bxh[c0] + bhh[c0];
  const float bs1 = bxh[c1] + bhh[c1];

  const float* a0 = emb + (long long)tok0*512 + lq*8;
  const float* a1 = emb + (long long)tok1*512 + lq*8;
  const float* b0 = Wxh + (long long)c0*512 + lq*8;
  const float* b1 = Wxh + (long long)c1*512 + lq*8;

  f32x4 acc00 = {0,0,0,0}, acc01 = {0,0,0,0}, acc10 = {0,0,0,0}, acc11 = {0,0,0,0};

  #pragma unroll
  for (int ks=0; ks<16; ++ks){
    half8 A0 = cvt8(a0 + ks*32);
    half8 A1 = cvt8(a1 + ks*32);
    half8 B0 = cvt8(b0 + ks*32);
    half8 B1 = cvt8(b1 + ks*32);
    acc00 = MFMA_F16(A0, B0, acc00);
    acc01 = MFMA_F16(A0, B1, acc01);
    acc10 = MFMA_F16(A1, B0, acc10);
    acc11 = MFMA_F16(A1, B1, acc11);
  }
  #pragma unroll
  for (int r=0; r<4; ++r){
    const long long m0 = mbase + 4*lq + r;
    const long long m1 = m0 + 16;
    out[m0*512 + c0] = acc00[r] + bs0;
    out[m0*512 + c1] = acc01[r] + bs1;
    out[m1*512 + c0] = acc10[r] + bs0;
    out[m1*512 + c1] = acc11[r] + bs1;
  }
}

// ---------------- Kernel 2: the recurrence (16-WG exchange) ----------------
// WG b: batch group g=b&3 (rows [16g,16g+16)), col slice s=b>>2 (cols [128s,128s+128)).
// mbox: [wg 16][buf 2][batch 16][32 u64]  (u64 = 4 fp16 cols). flags: [16] u32.
__global__ __launch_bounds__(256, 1) void k_rnn(
    const float* __restrict__ Whh,
    float* __restrict__ out,
    unsigned long long* __restrict__ mbox,
    unsigned int* __restrict__ flags)
{
  const int b   = blockIdx.x;
  const int g   = b & 3;
  const int s   = b >> 2;
  const int tid = threadIdx.x;
  const int w   = tid >> 6;        // wave: cols [128s+32w, +32) = 2 ct tiles
  const int l   = tid & 63;
  const int lr  = l & 15;          // batch index role (B-col j, D-col j)
  const int kg  = l >> 4;          // k-group

  const int wcol = s*128 + w*32;

  __shared__ _Float16 hb[2][16][128];   // own slice, 16B-chunk swizzled by (lr&7)

  // W frags (A-operand): lane -> Whh[col = wcol + 16ct + lr][k = 32ks + 8kg + e]
  half8 W0[16], W1[16];
  {
    const float* p0 = Whh + (long long)(wcol      + lr)*512 + kg*8;
    const float* p1 = Whh + (long long)(wcol + 16 + lr)*512 + kg*8;
    #pragma unroll
    for (int ks = 0; ks < 16; ++ks){
      W0[ks] = cvt8(p0 + ks*32);
      W1[ks] = cvt8(p1 + ks*32);
    }
  }

  const int ps0 = (s+1)&3, ps1 = (s+2)&3, ps2 = (s+3)&3;
  const int pb0 = g + 4*ps0, pb1 = g + 4*ps1, pb2 = g + 4*ps2;
  const int myp = (l==0) ? pb0 : (l==1) ? pb1 : pb2;

  unsigned long long* mb_me = mbox + (long long)b*1024;   // [buf 2][16][32]

  const long long nbase = (long long)(g*16 + lr) * (2048LL*512);

  for (int t = 0; t < 2048; ++t){
    const int bufc = t & 1, bufp = bufc ^ 1;

    // prefetch xh' (K1 output, same slot we'll overwrite with h_t)
    const float* op = out + nbase + (long long)t*512 + wcol + kg*4;
    f32x4 xh0 = *(const f32x4*)(op);
    f32x4 xh1 = *(const f32x4*)(op + 16);

    f32x4 acc0 = {0,0,0,0}, acc1 = {0,0,0,0};

    if (t > 0){
      // ---- poll: partners must have published h_{t-1} (flag >= t) ----
      {
        const unsigned tgt = (unsigned)t;
        int spin = 0; int done;
        do {
          unsigned v = tgt;
          if (l < 3) v = __hip_atomic_load(&flags[myp], __ATOMIC_RELAXED, __HIP_MEMORY_SCOPE_AGENT);
          done = __all((int)(v >= tgt));
        } while (!done && ++spin < (1<<20));
      }

      // ---- own slice from LDS (ks_global = 4s + ksl) ----
      const char* hbase = (const char*)&hb[bufp][lr][0];
      #pragma unroll
      for (int ksl = 0; ksl < 4; ++ksl){
        const int chunk = (4*ksl + kg) ^ (lr & 7);
        half8 hf = *(const half8*)(hbase + (chunk << 4));
        acc0 = MFMA_F16(W0[4*s + ksl], hf, acc0);
        acc1 = MFMA_F16(W1[4*s + ksl], hf, acc1);
      }

      // ---- partner slices from mailboxes ----
      #pragma unroll
      for (int pi = 0; pi < 3; ++pi){
        const int ps = (pi==0) ? ps0 : (pi==1) ? ps1 : ps2;
        const int pb = (pi==0) ? pb0 : (pi==1) ? pb1 : pb2;
        const unsigned long long* mp = mbox + (long long)pb*1024 + bufp*512 + lr*32;
        #pragma unroll
        for (int ksl = 0; ksl < 4; ++ksl){
          const int ui = 8*ksl + 2*kg;
          unsigned long long u0 = __hip_atomic_load(&mp[ui],   __ATOMIC_RELAXED, __HIP_MEMORY_SCOPE_AGENT);
          unsigned long long u1 = __hip_atomic_load(&mp[ui+1], __ATOMIC_RELAXED, __HIP_MEMORY_SCOPE_AGENT);
          union { unsigned long long u[2]; half8 v; } cv;
          cv.u[0] = u0; cv.u[1] = u1;
          acc0 = MFMA_F16(W0[4*ps + ksl], cv.v, acc0);
          acc1 = MFMA_F16(W1[4*ps + ksl], cv.v, acc1);
        }
      }
    }

    // ---- epilogue: h = tanh(acc + xh) ----
    f32x4 h0, h1;
    #pragma unroll
    for (int r = 0; r < 4; ++r){
      h0[r] = tanh_fast(acc0[r] + xh0[r]);
      h1[r] = tanh_fast(acc1[r] + xh1[r]);
    }
    union { _Float16 h[4]; unsigned long long u; } p0, p1;
    #pragma unroll
    for (int r = 0; r < 4; ++r){ p0.h[r] = (_Float16)h0[r]; p1.h[r] = (_Float16)h1[r]; }

    // own-slice LDS write (swizzled, same mapping as reads)
    {
      char* wb = (char*)&hb[bufc][lr][0];
      const int byte0 = 64*w + 8*kg;          // ct0: colLocal = 32w + 4kg
      const int byte1 = byte0 + 32;           // ct1
      const int c0 = byte0 >> 4, o0 = byte0 & 15;
      const int c1 = byte1 >> 4, o1 = byte1 & 15;
      *(unsigned long long*)(wb + (((c0 ^ (lr&7)) << 4) + o0)) = p0.u;
      *(unsigned long long*)(wb + (((c1 ^ (lr&7)) << 4) + o1)) = p1.u;
    }
    // mailbox publish (agent-scope atomic stores)
    {
      unsigned long long* mm = mb_me + bufc*512 + lr*32;
      const int ui = 8*w + kg;                 // u64 index of ct0 (ct1 at +4)
      __hip_atomic_store(&mm[ui],     p0.u, __ATOMIC_RELAXED, __HIP_MEMORY_SCOPE_AGENT);
      __hip_atomic_store(&mm[ui + 4], p1.u, __ATOMIC_RELAXED, __HIP_MEMORY_SCOPE_AGENT);
    }

    asm volatile("s_waitcnt vmcnt(0)" ::: "memory");  // mailbox globally performed
    __syncthreads();                                  // all waves drained + LDS coherent
    if (tid == 0)
      __hip_atomic_store(&flags[b], (unsigned)(t+1), __ATOMIC_RELAXED, __HIP_MEMORY_SCOPE_AGENT);

    // HBM out-stores AFTER the flag: never on the critical path, drained next step (free)
    *(f32x4*)(op)      = h0;
    *(f32x4*)(op + 16) = h1;
  }
}

extern "C" void kernel_launch(void* const* d_in, const int* in_sizes, int n_in,
                              void* d_out, int out_size, void* d_ws, size_t ws_size,
                              hipStream_t stream)
{
  const int*   X    = (const int*)  d_in[0];
  const float* emb  = (const float*)d_in[1];
  const float* Whh  = (const float*)d_in[2];
  const float* bhh  = (const float*)d_in[3];
  const float* Wxh  = (const float*)d_in[4];
  const float* bxh  = (const float*)d_in[5];
  float* out = (float*)d_out;

  unsigned long long* mbox  = (unsigned long long*)d_ws;                 // 131072 B
  unsigned int*       flags = (unsigned int*)((char*)d_ws + 131072);     // 64 B

  hipMemsetAsync(flags, 0, 16*sizeof(unsigned int), stream);
  hipLaunchKernelGGL(k_xh,  dim3(16384), dim3(256), 0, stream, X, emb, Wxh, bxh, bhh, out);
  hipLaunchKernelGGL(k_rnn, dim3(16),    dim3(256), 0, stream, Whh, out, mbox, flags);
}

// Round 5
// 11674.178 us; speedup vs baseline: 1.6214x; 1.6214x over previous
//
#include <hip/hip_runtime.h>

// RNN: h_t = tanh(W_hh h_{t-1} + b_hh + W_xh emb[X_t] + b_xh);  N=64, L=2048, H=512.
//
// K1: Xh' = emb[X] @ W_xh^T + (b_xh + b_hh) -> written INTO d_out (fp16 MFMA, fp32 accum).
// K2: 4 WGs (one per 16 batch rows) x 256 thr (4 waves, 1 wave/SIMD -> 512 regs/wave).
//     Wave w owns cols [128w,128w+128) = 128 W-frags:
//       64 frags FORCED into AGPRs ("a"-constraint asm MFMA reads them in place),
//       32 frags in VGPRs, 32 frags in LDS (128 KB, pre-formatted b128).
//     h in one 16 KB swizzled LDS buffer; 2 barriers/step; NO cross-WG traffic,
//     NO atomics, NO spill (AGPR class has no competing use).

typedef _Float16 half8 __attribute__((ext_vector_type(8)));
typedef float    f32x4 __attribute__((ext_vector_type(4)));

#define MFMA_F16(A,B,C) __builtin_amdgcn_mfma_f32_16x16x32_f16(A,B,C,0,0,0)

// MFMA with A-operand pinned in AGPRs (gfx950: A/B may come from VGPR or AGPR).
static __device__ __forceinline__ void mfma_agpr(f32x4& acc, half8 w, half8 h){
  asm volatile("v_mfma_f32_16x16x32_f16 %0, %1, %2, %0"
               : "+v"(acc) : "a"(w), "v"(h));
}

static __device__ __forceinline__ half8 cvt8(const float* p){
  const f32x4* q = (const f32x4*)p;
  f32x4 a = q[0], b = q[1];
  half8 r;
  r[0]=(_Float16)a[0]; r[1]=(_Float16)a[1]; r[2]=(_Float16)a[2]; r[3]=(_Float16)a[3];
  r[4]=(_Float16)b[0]; r[5]=(_Float16)b[1]; r[6]=(_Float16)b[2]; r[7]=(_Float16)b[3];
  return r;
}

static __device__ __forceinline__ float tanh_fast(float z){
  float e = __expf(2.0f*z);
  return 1.0f - 2.0f/(e + 1.0f);
}

// ---------------- Kernel 1: Xh' = E @ Wxh^T + (bxh + bhh) -> d_out ----------------
__global__ __launch_bounds__(256) void k_xh(
    const int* __restrict__ X, const float* __restrict__ emb,
    const float* __restrict__ Wxh, const float* __restrict__ bxh,
    const float* __restrict__ bhh, float* __restrict__ out)
{
  const int bid = blockIdx.x;
  const int bm = bid >> 3;
  const int bn = bid & 7;
  const int tid = threadIdx.x;
  const int w  = tid >> 6;
  const int l  = tid & 63;
  const int lr = l & 15, lq = l >> 4;

  const int mbase = bm*64 + (w>>1)*32;
  const int nbase = bn*64 + (w&1)*32;

  const int tok0 = X[mbase + lr];
  const int tok1 = X[mbase + 16 + lr];
  const int c0 = nbase + lr;
  const int c1 = nbase + 16 + lr;
  const float bs0 = bxh[c0] + bhh[c0];
  const float bs1 = bxh[c1] + bhh[c1];

  const float* a0 = emb + (long long)tok0*512 + lq*8;
  const float* a1 = emb + (long long)tok1*512 + lq*8;
  const float* b0 = Wxh + (long long)c0*512 + lq*8;
  const float* b1 = Wxh + (long long)c1*512 + lq*8;

  f32x4 acc00 = {0,0,0,0}, acc01 = {0,0,0,0}, acc10 = {0,0,0,0}, acc11 = {0,0,0,0};

  #pragma unroll
  for (int ks=0; ks<16; ++ks){
    half8 A0 = cvt8(a0 + ks*32);
    half8 A1 = cvt8(a1 + ks*32);
    half8 B0 = cvt8(b0 + ks*32);
    half8 B1 = cvt8(b1 + ks*32);
    acc00 = MFMA_F16(A0, B0, acc00);
    acc01 = MFMA_F16(A0, B1, acc01);
    acc10 = MFMA_F16(A1, B0, acc10);
    acc11 = MFMA_F16(A1, B1, acc11);
  }
  #pragma unroll
  for (int r=0; r<4; ++r){
    const long long m0 = mbase + 4*lq + r;
    const long long m1 = m0 + 16;
    out[m0*512 + c0] = acc00[r] + bs0;
    out[m0*512 + c1] = acc01[r] + bs1;
    out[m1*512 + c0] = acc10[r] + bs0;
    out[m1*512 + c1] = acc11[r] + bs1;
  }
}

// ---------------- Kernel 2: the recurrence ----------------
__global__ __launch_bounds__(256, 1) void k_rnn(
    const float* __restrict__ Whh,
    float* __restrict__ out)
{
  const int g   = blockIdx.x;          // batch rows [16g, 16g+16)
  const int tid = threadIdx.x;
  const int w   = tid >> 6;            // wave 0..3: cols [128w, 128w+128)
  const int l   = tid & 63;
  const int lr  = l & 15;              // A-row (h-out col) / B-col (batch) / D-col (batch)
  const int kg  = l >> 4;              // k-group
  const int r7  = lr & 7;
  const int colb = 128*w;

  __shared__ _Float16 wlds[4][32][512];  // 128 KB: [wave][frag][lane*8halfs]
  __shared__ _Float16 hb[16][512];       // 16 KB: h(t), 16B-chunk XOR-swizzled per row

  // zero h0
  {
    f32x4 z = {0,0,0,0};
    f32x4* hz = (f32x4*)&hb[0][0];
    for (int i = tid; i < 1024; i += 256) hz[i] = z;
  }

  // Load W frags: frag(ct,ks): lane -> Whh[col = colb+16ct+lr][k = 32ks+8kg+e].
  // f = ct*16+ks:  f even -> AGPR (64) ;  f%4==1 -> VGPR (32) ;  f%4==3 -> LDS (32).
  half8 Wa[64], Wv[32];
  #pragma unroll
  for (int ct = 0; ct < 8; ++ct){
    const float* wp = Whh + (long long)(colb + ct*16 + lr)*512 + kg*8;
    #pragma unroll
    for (int ks = 0; ks < 16; ++ks){
      half8 v = cvt8(wp + ks*32);
      const int f = ct*16 + ks;
      if ((f & 1) == 0){ asm("" : "+a"(v)); Wa[f>>1] = v; }
      else if ((f & 3) == 1){ Wv[f>>2] = v; }
      else { *(half8*)&wlds[w][f>>2][l*8] = v; }
    }
  }
  __syncthreads();

  const long long nb = (long long)(g*16 + lr) * (2048LL*512);

  for (int t = 0; t < 2048; ++t){
    // prefetch xh' (K1 output; consumed in epilogue ~2000 cy later)
    const float* op = out + nb + (long long)t*512 + colb + kg*4;
    f32x4 xh[8];
    #pragma unroll
    for (int ct = 0; ct < 8; ++ct) xh[ct] = *(const f32x4*)(op + ct*16);

    f32x4 acc[8];
    #pragma unroll
    for (int ct = 0; ct < 8; ++ct) acc[ct] = (f32x4){0,0,0,0};

    // MFMA phase: B-frag = h[batch=lr][k=32ks+8kg+e], swizzled chunk (4ks+kg)^r7
    const char* hrow = (const char*)&hb[lr][0];
    #pragma unroll
    for (int ks = 0; ks < 16; ++ks){
      half8 hf = *(const half8*)(hrow + (((4*ks + kg) ^ r7) << 4));
      #pragma unroll
      for (int ct = 0; ct < 8; ++ct){
        const int f = ct*16 + ks;
        if ((f & 1) == 0)       mfma_agpr(acc[ct], Wa[f>>1], hf);
        else if ((f & 3) == 1)  acc[ct] = MFMA_F16(Wv[f>>2], hf, acc[ct]);
        else {
          half8 wl = *(const half8*)&wlds[w][f>>2][l*8];
          acc[ct] = MFMA_F16(wl, hf, acc[ct]);
        }
      }
    }
    __syncthreads();   // all waves done reading h(t-1)

    // epilogue: lane holds D[i=4kg+r][j=lr] per ct -> col = colb+16ct+4kg+r, batch lr
    #pragma unroll
    for (int ct = 0; ct < 8; ++ct){
      f32x4 hv;
      #pragma unroll
      for (int r = 0; r < 4; ++r) hv[r] = tanh_fast(acc[ct][r] + xh[ct][r]);
      *(f32x4*)(op + ct*16) = hv;

      union { _Float16 h[4]; unsigned long long u; } pk;
      #pragma unroll
      for (int r = 0; r < 4; ++r) pk.h[r] = (_Float16)hv[r];
      const int byte = (colb + ct*16 + kg*4) * 2;
      char* wrow = (char*)&hb[lr][0];
      *(unsigned long long*)(wrow + ((((byte >> 4) ^ r7) << 4) + (byte & 15))) = pk.u;
    }
    __syncthreads();   // h(t) visible to all waves
  }
}

extern "C" void kernel_launch(void* const* d_in, const int* in_sizes, int n_in,
                              void* d_out, int out_size, void* d_ws, size_t ws_size,
                              hipStream_t stream)
{
  const int*   X    = (const int*)  d_in[0];
  const float* emb  = (const float*)d_in[1];
  const float* Whh  = (const float*)d_in[2];
  const float* bhh  = (const float*)d_in[3];
  const float* Wxh  = (const float*)d_in[4];
  const float* bxh  = (const float*)d_in[5];
  float* out = (float*)d_out;

  hipLaunchKernelGGL(k_xh,  dim3(16384), dim3(256), 0, stream, X, emb, Wxh, bxh, bhh, out);
  hipLaunchKernelGGL(k_rnn, dim3(4),     dim3(256), 0, stream, Whh, out);
}

// Round 9
// 8250.982 us; speedup vs baseline: 2.2941x; 1.4149x over previous
//
#include <hip/hip_runtime.h>

// RNN: h_t = tanh(W_hh h_{t-1} + b_hh + W_xh emb[X_t] + b_xh);  N=64, L=2048, H=512.
//
// K1: Xh' = emb[X] @ W_xh^T + (b_xh + b_hh) -> written INTO d_out (fp16 MFMA, fp32 accum).
// K2: 4 WGs x 256 thr (4 waves, 1 wave/SIMD). Wave w owns cols [128w,128w+128).
//     W frags: 64 AGPR + 32 VGPR + 32 LDS per wave (R5-verified mapping, FETCH=133MB).
//     R9: ENTIRE inner loop is hand-scheduled volatile asm -- ds_read_b128 with
//     immediate offsets, counted s_waitcnt lgkmcnt(N) (DS returns in-order),
//     volatile MFMAs, s_nop hazard guards at asm<->C++ boundaries. xh prefetched
//     one FULL step ahead via asm global_load, fenced by vmcnt(0) with "+v" ties.
//     h-buffer hb2[ks][lane][8] = B-frag-native, conflict-free, offset=ks*1024.

typedef _Float16 half8 __attribute__((ext_vector_type(8)));
typedef float    f32x4 __attribute__((ext_vector_type(4)));

#define MFMA_F16(A,B,C) __builtin_amdgcn_mfma_f32_16x16x32_f16(A,B,C,0,0,0)

// all-volatile manual pipeline primitives
#define MFA(c, A, B) asm volatile("v_mfma_f32_16x16x32_f16 %0, %1, %2, %0" : "+v"(c) : "a"(A), "v"(B))
#define MFV(c, A, B) asm volatile("v_mfma_f32_16x16x32_f16 %0, %1, %2, %0" : "+v"(c) : "v"(A), "v"(B))
#define DSR(d, a, o) asm volatile("ds_read_b128 %0, %1 offset:" o : "=v"(d) : "v"(a))
#define WTL(s)       asm volatile("s_waitcnt lgkmcnt(" s ")")
#define GLD(d, p)    asm volatile("global_load_dwordx4 %0, %1, off" : "=v"(d) : "v"(p))

#define M8A(i, h) do{ _Pragma("unroll") for(int ct=0;ct<8;++ct) MFA(acc[ct], Wa[ct*8+(i)], (h)); }while(0)
#define M8V(i, h) do{ _Pragma("unroll") for(int ct=0;ct<8;++ct) MFV(acc[ct], Wv[ct*4+(i)], (h)); }while(0)
#define M8L(h)    do{ _Pragma("unroll") for(int ct=0;ct<8;++ct) MFV(acc[ct], wq[ct], (h)); }while(0)

static __device__ __forceinline__ half8 cvt8(const float* p){
  const f32x4* q = (const f32x4*)p;
  f32x4 a = q[0], b = q[1];
  half8 r;
  r[0]=(_Float16)a[0]; r[1]=(_Float16)a[1]; r[2]=(_Float16)a[2]; r[3]=(_Float16)a[3];
  r[4]=(_Float16)b[0]; r[5]=(_Float16)b[1]; r[6]=(_Float16)b[2]; r[7]=(_Float16)b[3];
  return r;
}

static __device__ __forceinline__ float tanh_fast(float z){
  float e = __expf(2.0f*z);
  return 1.0f - 2.0f/(e + 1.0f);
}

// ---------------- Kernel 1: Xh' = E @ Wxh^T + (bxh + bhh) -> d_out ----------------
__global__ __launch_bounds__(256) void k_xh(
    const int* __restrict__ X, const float* __restrict__ emb,
    const float* __restrict__ Wxh, const float* __restrict__ bxh,
    const float* __restrict__ bhh, float* __restrict__ out)
{
  const int bid = blockIdx.x;
  const int bm = bid >> 3;
  const int bn = bid & 7;
  const int tid = threadIdx.x;
  const int w  = tid >> 6;
  const int l  = tid & 63;
  const int lr = l & 15, lq = l >> 4;

  const int mbase = bm*64 + (w>>1)*32;
  const int nbase = bn*64 + (w&1)*32;

  const int tok0 = X[mbase + lr];
  const int tok1 = X[mbase + 16 + lr];
  const int c0 = nbase + lr;
  const int c1 = nbase + 16 + lr;
  const float bs0 = bxh[c0] + bhh[c0];
  const float bs1 = bxh[c1] + bhh[c1];

  const float* a0 = emb + (long long)tok0*512 + lq*8;
  const float* a1 = emb + (long long)tok1*512 + lq*8;
  const float* b0 = Wxh + (long long)c0*512 + lq*8;
  const float* b1 = Wxh + (long long)c1*512 + lq*8;

  f32x4 acc00 = {0,0,0,0}, acc01 = {0,0,0,0}, acc10 = {0,0,0,0}, acc11 = {0,0,0,0};

  #pragma unroll
  for (int ks=0; ks<16; ++ks){
    half8 A0 = cvt8(a0 + ks*32);
    half8 A1 = cvt8(a1 + ks*32);
    half8 B0 = cvt8(b0 + ks*32);
    half8 B1 = cvt8(b1 + ks*32);
    acc00 = MFMA_F16(A0, B0, acc00);
    acc01 = MFMA_F16(A0, B1, acc01);
    acc10 = MFMA_F16(A1, B0, acc10);
    acc11 = MFMA_F16(A1, B1, acc11);
  }
  #pragma unroll
  for (int r=0; r<4; ++r){
    const long long m0 = mbase + 4*lq + r;
    const long long m1 = m0 + 16;
    out[m0*512 + c0] = acc00[r] + bs0;
    out[m0*512 + c1] = acc01[r] + bs1;
    out[m1*512 + c0] = acc10[r] + bs0;
    out[m1*512 + c1] = acc11[r] + bs1;
  }
}

// ---------------- Kernel 2: the recurrence ----------------
__global__ __launch_bounds__(256, 1) void k_rnn(
    const float* __restrict__ Whh,
    float* __restrict__ out)
{
  const int g   = blockIdx.x;          // batch rows [16g, 16g+16)
  const int tid = threadIdx.x;
  const int w   = tid >> 6;            // wave 0..3: cols [128w, 128w+128)
  const int l   = tid & 63;
  const int lr  = l & 15;              // batch index (B-col j / D-col j)
  const int kg  = l >> 4;              // k-group
  const int colb = 128*w;

  __shared__ _Float16 wlds[4][32][512];  // 128 KB: [wave][frag][lane*8halfs]
  __shared__ _Float16 hb2[16][64][8];    // 16 KB: h as native B-frags [ks][lane][elem]

  // zero h0
  {
    f32x4 z = {0,0,0,0};
    f32x4* hz = (f32x4*)&hb2[0][0][0];
    for (int i = tid; i < 1024; i += 256) hz[i] = z;
  }

  // W frags (R5-identical): frag(ct,ks): lane -> Whh[col=colb+16ct+lr][k=32ks+8kg+e].
  // f = ct*16+ks: f even -> AGPR(64); f%4==1 -> VGPR(32); f%4==3 -> LDS(32).
  half8 Wa[64], Wv[32];
  #pragma unroll
  for (int ct = 0; ct < 8; ++ct){
    const float* wp = Whh + (long long)(colb + ct*16 + lr)*512 + kg*8;
    #pragma unroll
    for (int ks = 0; ks < 16; ++ks){
      half8 v = cvt8(wp + ks*32);
      const int f = ct*16 + ks;
      if ((f & 1) == 0){ asm("" : "+a"(v)); Wa[f>>1] = v; }
      else if ((f & 3) == 1){ Wv[f>>2] = v; }
      else { *(half8*)&wlds[w][f>>2][l*8] = v; }
    }
  }
  __syncthreads();

  // LDS byte addresses (generic->32b truncation = LDS offset; aperture is 4GB-aligned)
  const unsigned ah = (unsigned)(unsigned long long)&hb2[0][l][0];        // + ks*1024
  const unsigned aw = (unsigned)(unsigned long long)&wlds[w][0][l*8];     // + frag*1024

  const long long nb = (long long)(g*16 + lr) * (2048LL*512) + colb + kg*4;

  // xh prefetch for t=0 (one full step of cover from here on)
  f32x4 xh[8];
  {
    const float* p0 = out + nb;
    #pragma unroll
    for (int ct = 0; ct < 8; ++ct) GLD(xh[ct], p0 + ct*16);
  }

  for (int t = 0; t < 2048; ++t){
    const float* op = out + nb + (long long)t*512;

    f32x4 acc[8];
    #pragma unroll
    for (int ct = 0; ct < 8; ++ct) acc[ct] = (f32x4){0,0,0,0};

    half8 hx[16]; half8 wq[8];
    // ---- hand-scheduled pipeline: hf 2-ahead, wl groups 2-blocks-ahead ----
    DSR(hx[0], ah, "0");   DSR(hx[1], ah, "1024");
    // ks0
    DSR(hx[2], ah, "2048");
    WTL("2"); asm volatile("s_nop 1");               // v_mov(acc)->MFMA SrcC guard
    M8A(0, hx[0]);
    // ks1  (wl group q0 for ks3: frags ct*4+0)
    DSR(wq[0], aw, "0");     DSR(wq[1], aw, "4096");  DSR(wq[2], aw, "8192");  DSR(wq[3], aw, "12288");
    DSR(hx[3], ah, "3072");
    WTL("6");
    M8V(0, hx[1]);
    // ks2
    DSR(wq[4], aw, "16384"); DSR(wq[5], aw, "20480"); DSR(wq[6], aw, "24576"); DSR(wq[7], aw, "28672");
    DSR(hx[4], ah, "4096");
    WTL("10");
    M8A(1, hx[2]);
    // ks3
    DSR(hx[5], ah, "5120");
    WTL("2");
    M8L(hx[3]);
    // ks4
    DSR(hx[6], ah, "6144");
    WTL("2");
    M8A(2, hx[4]);
    // ks5  (wl q1 for ks7: frags ct*4+1)
    DSR(wq[0], aw, "1024");  DSR(wq[1], aw, "5120");  DSR(wq[2], aw, "9216");  DSR(wq[3], aw, "13312");
    DSR(hx[7], ah, "7168");
    WTL("6");
    M8V(1, hx[5]);
    // ks6
    DSR(wq[4], aw, "17408"); DSR(wq[5], aw, "21504"); DSR(wq[6], aw, "25600"); DSR(wq[7], aw, "29696");
    DSR(hx[8], ah, "8192");
    WTL("10");
    M8A(3, hx[6]);
    // ks7
    DSR(hx[9], ah, "9216");
    WTL("2");
    M8L(hx[7]);
    // ks8
    DSR(hx[10], ah, "10240");
    WTL("2");
    M8A(4, hx[8]);
    // ks9  (wl q2 for ks11: frags ct*4+2)
    DSR(wq[0], aw, "2048");  DSR(wq[1], aw, "6144");  DSR(wq[2], aw, "10240"); DSR(wq[3], aw, "14336");
    DSR(hx[11], ah, "11264");
    WTL("6");
    M8V(2, hx[9]);
    // ks10
    DSR(wq[4], aw, "18432"); DSR(wq[5], aw, "22528"); DSR(wq[6], aw, "26624"); DSR(wq[7], aw, "30720");
    DSR(hx[12], ah, "12288");
    WTL("10");
    M8A(5, hx[10]);
    // ks11
    DSR(hx[13], ah, "13312");
    WTL("2");
    M8L(hx[11]);
    // ks12
    DSR(hx[14], ah, "14336");
    WTL("2");
    M8A(6, hx[12]);
    // ks13 (wl q3 for ks15: frags ct*4+3)
    DSR(wq[0], aw, "3072");  DSR(wq[1], aw, "7168");  DSR(wq[2], aw, "11264"); DSR(wq[3], aw, "15360");
    DSR(hx[15], ah, "15360");
    WTL("6");
    M8V(3, hx[13]);
    // ks14
    DSR(wq[4], aw, "19456"); DSR(wq[5], aw, "23552"); DSR(wq[6], aw, "27648"); DSR(wq[7], aw, "31744");
    WTL("9");
    M8A(7, hx[14]);
    // ks15
    WTL("0");
    M8L(hx[15]);

    // MFMA -> VALU read hazard guard, then xh fence (ties xh so tanh can't hoist)
    asm volatile("s_nop 7\n\ts_nop 7");
    asm volatile("s_waitcnt vmcnt(0)"
                 : "+v"(xh[0]), "+v"(xh[1]), "+v"(xh[2]), "+v"(xh[3]),
                   "+v"(xh[4]), "+v"(xh[5]), "+v"(xh[6]), "+v"(xh[7]));

    // epilogue: h = tanh(acc + xh); fp32 out; prefetch next xh
    f32x4 hv[8];
    #pragma unroll
    for (int ct = 0; ct < 8; ++ct){
      #pragma unroll
      for (int r = 0; r < 4; ++r) hv[ct][r] = tanh_fast(acc[ct][r] + xh[ct][r]);
      *(f32x4*)(op + ct*16) = hv[ct];
    }
    if (t < 2047){
      const float* np = op + 512;
      #pragma unroll
      for (int ct = 0; ct < 8; ++ct) GLD(xh[ct], np + ct*16);
    }

    __syncthreads();   // #1: all waves done reading hb2(t-1)

    // hb2 write: value (batch lr, col c=colb+16ct+4kg+r) ->
    //   ks_r = 4w+(ct>>1); lane_r = (2(ct&1)+(kg>>1))*16+lr; byte = 8(kg&1) (+2r inside u64)
    #pragma unroll
    for (int ct = 0; ct < 8; ++ct){
      union { _Float16 h[4]; unsigned long long u; } pk;
      #pragma unroll
      for (int r = 0; r < 4; ++r) pk.h[r] = (_Float16)hv[ct][r];
      const int ks_r   = 4*w + (ct>>1);
      const int lane_r = (2*(ct&1) + (kg>>1))*16 + lr;
      *(unsigned long long*)((char*)&hb2[ks_r][lane_r][0] + 8*(kg&1)) = pk.u;
    }

    __syncthreads();   // #2: h(t) visible to all waves
  }
}

extern "C" void kernel_launch(void* const* d_in, const int* in_sizes, int n_in,
                              void* d_out, int out_size, void* d_ws, size_t ws_size,
                              hipStream_t stream)
{
  const int*   X    = (const int*)  d_in[0];
  const float* emb  = (const float*)d_in[1];
  const float* Whh  = (const float*)d_in[2];
  const float* bhh  = (const float*)d_in[3];
  const float* Wxh  = (const float*)d_in[4];
  const float* bxh  = (const float*)d_in[5];
  float* out = (float*)d_out;

  hipLaunchKernelGGL(k_xh,  dim3(16384), dim3(256), 0, stream, X, emb, Wxh, bxh, bhh, out);
  hipLaunchKernelGGL(k_rnn, dim3(4),     dim3(256), 0, stream, Whh, out);
}